// Round 4
// baseline (412.343 us; speedup 1.0000x reference)
//
#include <hip/hip_runtime.h>

#define LOGZERO -4290774016.0f   // -(65504^2), exactly representable in fp32

constexpr int Bb = 32, Tt = 512, Dd = 512, Vv = 4096;
constexpr int BT = Bb * Tt;

typedef __attribute__((ext_vector_type(8))) short short8;
typedef __attribute__((ext_vector_type(4))) float f32x4;

#define GLOBAL_AS __attribute__((address_space(1)))
#define LDS_AS    __attribute__((address_space(3)))

__device__ __forceinline__ unsigned short f2bf(float f) {
  unsigned int u = __float_as_uint(f);
  u += 0x7FFFu + ((u >> 16) & 1u);   // RNE
  return (unsigned short)(u >> 16);
}

__device__ __forceinline__ float lgadd(float a, float b) {
  float mx = fmaxf(a, b);
  float d  = fabsf(a - b);
  return mx + __logf(1.0f + __expf(-d));
}

// ---- x and W fp32 -> bf16 (one pass) ----
__global__ __launch_bounds__(256) void kConv(const float* __restrict__ x,
                                             const float* __restrict__ W,
                                             unsigned short* __restrict__ Xb,
                                             unsigned short* __restrict__ Wb) {
  size_t i = (size_t)(blockIdx.x * 256 + threadIdx.x) * 4;
  const float* src;
  unsigned short* dst;
  if (i < (size_t)BT * Dd) { src = x + i; dst = Xb + i; }
  else { size_t j = i - (size_t)BT * Dd; src = W + j; dst = Wb + j; }
  float4 v = *(const float4*)src;
  ushort4 h;
  h.x = f2bf(v.x); h.y = f2bf(v.y); h.z = f2bf(v.z); h.w = f2bf(v.w);
  *(ushort4*)dst = h;
}

// ---- barrier-free GEMM + fused exp-sum ----
// Block = 64 rows x 512 cols, full K=512. A resident in LDS (staged once via
// DMA); B streamed global->register (no barriers in K-loop). grid 2048:
// tileN = blk&7 pins each 0.5MB B-stripe to one XCD's L2.
__global__ __launch_bounds__(256, 2) void kA(const unsigned short* __restrict__ Xb,
                                             const unsigned short* __restrict__ Wb,
                                             const float* __restrict__ bias,
                                             float* __restrict__ Ssum) {
  __shared__ unsigned short Ald[64 * 512];   // 64 KB, xor-swizzled 16B groups
  const int tid = threadIdx.x;
  const int tileN = blockIdx.x & 7;
  const int tileM = blockIdx.x >> 3;
  const int row0 = tileM * 64, col0 = tileN * 512;

  const int lane = tid & 63, w = tid >> 6;
  const int ln15 = lane & 15, quad = lane >> 4;

  // stage A: wave w stages rows w*16 .. w*16+15 (one 1KB row per DMA inst)
  #pragma unroll
  for (int i = 0; i < 16; ++i) {
    int r = w * 16 + i;
    int kk = (lane ^ (r & 7)) << 3;          // low-3-bit XOR swizzle on 16B groups
    const unsigned short* gp = Xb + (size_t)(row0 + r) * Dd + kk;
    unsigned short* lp = Ald + r * 512;      // wave-uniform base; lane*16B appended by HW
    __builtin_amdgcn_global_load_lds((const GLOBAL_AS void*)gp,
                                     (LDS_AS void*)lp, 16, 0, 0);
  }
  __syncthreads();                           // only barrier in the kernel

  const int colw = col0 + w * 128;
  f32x4 acc[8][4];
  #pragma unroll
  for (int ct = 0; ct < 8; ++ct)
    #pragma unroll
    for (int rt = 0; rt < 4; ++rt) acc[ct][rt] = {0.f, 0.f, 0.f, 0.f};

  for (int ks = 0; ks < 16; ++ks) {
    short8 af[4];
    #pragma unroll
    for (int rt = 0; rt < 4; ++rt) {
      int r = rt * 16 + ln15;
      int phys = (ks * 4 + quad) ^ (r & 7);
      af[rt] = *(const short8*)&Ald[r * 512 + (phys << 3)];
    }
    #pragma unroll
    for (int ct = 0; ct < 8; ++ct) {
      short8 bf = *(const short8*)&Wb[(size_t)(colw + ct * 16 + ln15) * Dd + ks * 32 + quad * 8];
      #pragma unroll
      for (int rt = 0; rt < 4; ++rt)
        acc[ct][rt] = __builtin_amdgcn_mfma_f32_16x16x32_bf16(af[rt], bf, acc[ct][rt], 0, 0, 0);
    }
  }

  // epilogue: row-wise sum over this wave's 128 cols of exp(logit+bias)
  float bv[8];
  #pragma unroll
  for (int ct = 0; ct < 8; ++ct) bv[ct] = bias[colw + ct * 16 + ln15];

  #pragma unroll
  for (int rt = 0; rt < 4; ++rt) {
    #pragma unroll
    for (int r = 0; r < 4; ++r) {
      float s = 0.f;
      #pragma unroll
      for (int ct = 0; ct < 8; ++ct) s += __expf(acc[ct][rt][r] + bv[ct]);
      s += __shfl_xor(s, 1, 64);
      s += __shfl_xor(s, 2, 64);
      s += __shfl_xor(s, 4, 64);
      s += __shfl_xor(s, 8, 64);
      if (ln15 == 0)
        atomicAdd(&Ssum[row0 + rt * 16 + quad * 4 + r], s);
    }
  }
}

// ---- selected-column RAW logits (blank + 30 beams), fp32 ----
// grid: BT/16 blocks, 256 threads. thread = (sel lane 0..31, bt-pair 0..7).
__global__ __launch_bounds__(256) void kB(const float* __restrict__ x,
                                          const float* __restrict__ W,
                                          const float* __restrict__ bias,
                                          const int* __restrict__ beam,
                                          const int* __restrict__ blankp,
                                          float* __restrict__ selL,
                                          int CB) {
  __shared__ float Wlds[31 * 516];
  __shared__ int   selv[32];
  __shared__ float biasv[32];
  const int tid = threadIdx.x;
  const int btbase = blockIdx.x * 16;
  const int b = btbase >> 9;          // 16 | 512 so whole block is one b
  if (tid < 31) {
    int v = (tid == 0) ? *blankp : beam[b * CB + tid - 1];
    selv[tid] = v;
    biasv[tid] = bias[v];
  }
  __syncthreads();
  for (int i = tid; i < 31 * 128; i += 256) {
    int s = i >> 7, c4 = i & 127;
    float4 w4 = *(const float4*)&W[(size_t)selv[s] * Dd + c4 * 4];
    *(float4*)&Wlds[s * 516 + c4 * 4] = w4;
  }
  __syncthreads();
  const int sx = tid & 31, pair = tid >> 5;
  const int kk = (sx < 31) ? sx : 30;
  const int bt0 = btbase + pair * 2, bt1 = bt0 + 1;
  const float4* x40 = (const float4*)&x[(size_t)bt0 * Dd];
  const float4* x41 = (const float4*)&x[(size_t)bt1 * Dd];
  float a0 = 0.f, a1 = 0.f;
  for (int i4 = 0; i4 < 128; ++i4) {
    float4 w4 = *(const float4*)&Wlds[kk * 516 + i4 * 4];
    float4 u = x40[i4];
    float4 v = x41[i4];
    a0 += w4.x * u.x + w4.y * u.y + w4.z * u.z + w4.w * u.w;
    a1 += w4.x * v.x + w4.y * v.y + w4.z * v.z + w4.w * v.w;
  }
  if (sx < 31) {
    selL[(size_t)bt0 * 31 + sx] = a0 + biasv[sx];   // RAW logit (no -log Ssum)
    selL[(size_t)bt1 * 31 + sx] = a1 + biasv[sx];
  }
}

// ---- CTC DP + output assembly. grid: B blocks x 256 threads ----
__global__ __launch_bounds__(256) void kC(const float* __restrict__ selL,
                                          const float* __restrict__ Ssum,
                                          const int* __restrict__ xl,
                                          const int* __restrict__ beam,
                                          const int* __restrict__ blankp,
                                          const int* __restrict__ eosp,
                                          float* __restrict__ out,
                                          int Ly, int CB) {
  __shared__ float sl[Tt * 31];     // 63.5 KB raw selected logits
  __shared__ float lgS[Tt];
  __shared__ float lastP1[Tt];
  __shared__ float blankLp[Tt];
  const int b = blockIdx.x, tid = threadIdx.x;

  for (int i = tid; i < Tt * 31; i += 256) sl[i] = selL[(size_t)b * Tt * 31 + i];
  for (int t = tid; t < Tt; t += 256) lgS[t] = __logf(Ssum[b * Tt + t]);
  __syncthreads();

  float* orow = out + (size_t)b * Vv;
  for (int i = tid; i < Vv; i += 256) orow[i] = LOGZERO;

  const int xlb = xl[b];
  float curP = LOGZERO;
  if (tid < 64) {
    const int lane = tid;
    float vloc[8];
    float run = 0.f;
    #pragma unroll
    for (int u = 0; u < 8; ++u) {
      int t = lane * 8 + u;
      float bl = sl[t * 31] - lgS[t];
      blankLp[t] = bl;
      run += bl;
      vloc[u] = run;
    }
    float inc = run;
    #pragma unroll
    for (int off = 1; off < 64; off <<= 1) {
      float o = __shfl_up(inc, off, 64);
      if (lane >= off) inc += o;
    }
    float excl = inc - run;
    #pragma unroll
    for (int u = 0; u < 8; ++u) lastP1[lane * 8 + u] = vloc[u] + excl;

    const int kk = (lane < CB) ? lane : (CB - 1);
    float Pn = LOGZERO, Pb = LOGZERO;
    float mrun = -3.0e38f, srun = 0.0f;
    int start = (Ly < Tt - 1) ? Ly : (Tt - 1);
    if (start == 0) {
      Pn = sl[1 + kk] - lgS[0];
      float vv = (0 < xlb) ? lgadd(Pn, Pb) : LOGZERO;
      float nm = fmaxf(mrun, vv);
      srun = srun * __expf(mrun - nm) + __expf(vv - nm);
      mrun = nm;
    }
    int t0 = (start > 1) ? start : 1;
    for (int t = t0; t < Tt; ++t) {
      float xn = sl[t * 31 + 1 + kk] - lgS[t];
      float xb = blankLp[t];
      float pref = lastP1[t - 1];   // lastPsum == lastP1 bit-exactly
      float Pn2 = lgadd(Pn, pref) + xn;
      float Pb2 = lgadd(Pn, Pb) + xb;
      Pn = Pn2; Pb = Pb2;
      float vv = (t < xlb) ? lgadd(Pn, Pb) : LOGZERO;
      float nm = fmaxf(mrun, vv);
      srun = srun * __expf(mrun - nm) + __expf(vv - nm);
      mrun = nm;
    }
    curP = mrun + __logf(srun);
  }
  __syncthreads();   // LOGZERO fill + lastP1 complete

  if (tid < 64) {
    if (tid < CB) orow[beam[b * CB + tid]] = curP;
  }
  __syncthreads();
  if (tid == 0) {
    float eosv = (xlb >= 1) ? lastP1[xlb - 1] : 0.0f;
    orow[*eosp] = eosv;
    orow[*blankp] = LOGZERO;
  }
}

extern "C" void kernel_launch(void* const* d_in, const int* in_sizes, int n_in,
                              void* d_out, int out_size, void* d_ws, size_t ws_size,
                              hipStream_t stream) {
  (void)n_in; (void)out_size; (void)ws_size;
  const float* x    = (const float*)d_in[0];
  const float* W    = (const float*)d_in[1];
  const float* bias = (const float*)d_in[2];
  const int* xl     = (const int*)d_in[3];
  const int* beam   = (const int*)d_in[5];
  const int* blankp = (const int*)d_in[6];
  const int* eosp   = (const int*)d_in[7];
  const int Ly = in_sizes[4] / Bb;
  const int CB = in_sizes[5] / Bb;

  float* Ssum = (float*)d_ws;                                        // 64 KB
  float* selL = (float*)((char*)d_ws + (size_t)65536);               // BT*31*4 = 1.94 MB
  unsigned short* Xbf = (unsigned short*)((char*)d_ws + (size_t)2097152);   // 16 MB
  unsigned short* Wbf = (unsigned short*)((char*)d_ws + (size_t)18874368);  // 4 MB
  float* outf = (float*)d_out;

  hipMemsetAsync(Ssum, 0, BT * sizeof(float), stream);
  kConv<<<(BT * Dd + Vv * Dd) / 1024, 256, 0, stream>>>(x, W, Xbf, Wbf);
  kB<<<BT / 16, 256, 0, stream>>>(x, W, bias, beam, blankp, selL, CB);
  kA<<<(BT / 64) * (Vv / 512), 256, 0, stream>>>(Xbf, Wbf, bias, Ssum);
  kC<<<Bb, 256, 0, stream>>>(selL, Ssum, xl, beam, blankp, eosp, outf, Ly, CB);
}

// Round 5
// 375.829 us; speedup vs baseline: 1.0972x; 1.0972x over previous
//
#include <hip/hip_runtime.h>

#define LOGZERO -4290774016.0f   // -(65504^2), exactly representable in fp32

constexpr int Bb = 32, Tt = 512, Dd = 512, Vv = 4096;
constexpr int BT = Bb * Tt;

typedef __attribute__((ext_vector_type(8))) short short8;
typedef __attribute__((ext_vector_type(4))) float f32x4;

#define GLOBAL_AS __attribute__((address_space(1)))
#define LDS_AS    __attribute__((address_space(3)))

__device__ __forceinline__ unsigned short f2bf(float f) {
  unsigned int u = __float_as_uint(f);
  u += 0x7FFFu + ((u >> 16) & 1u);   // RNE
  return (unsigned short)(u >> 16);
}

__device__ __forceinline__ float lgadd(float a, float b) {
  float mx = fmaxf(a, b);
  float d  = fabsf(a - b);
  return mx + __logf(1.0f + __expf(-d));
}

// ---- x and W fp32 -> bf16 (one pass) ----
__global__ __launch_bounds__(256) void kConv(const float* __restrict__ x,
                                             const float* __restrict__ W,
                                             unsigned short* __restrict__ Xb,
                                             unsigned short* __restrict__ Wb) {
  size_t i = (size_t)(blockIdx.x * 256 + threadIdx.x) * 4;
  const float* src;
  unsigned short* dst;
  if (i < (size_t)BT * Dd) { src = x + i; dst = Xb + i; }
  else { size_t j = i - (size_t)BT * Dd; src = W + j; dst = Wb + j; }
  float4 v = *(const float4*)src;
  ushort4 h;
  h.x = f2bf(v.x); h.y = f2bf(v.y); h.z = f2bf(v.z); h.w = f2bf(v.w);
  *(ushort4*)dst = h;
}

// ---- barrier-free GEMM + fused exp-sum, M_tile=128 ----
// Block = 128 rows x 512 cols, full K=512. A resident in 128 KB LDS (staged
// once via DMA, only one barrier); B streamed global->register with explicit
// 1-step software pipeline. 8 waves: wave w = cols [col0+w*64, +64).
// grid 1024: tileN = blk&7 pins each 0.5MB B-stripe to one XCD's L2.
__global__ __launch_bounds__(512, 2) void kA(const unsigned short* __restrict__ Xb,
                                             const unsigned short* __restrict__ Wb,
                                             const float* __restrict__ bias,
                                             float* __restrict__ Ssum) {
  __shared__ unsigned short Ald[128 * 512];   // 128 KB, xor-swizzled 16B groups
  const int tid = threadIdx.x;
  const int tileN = blockIdx.x & 7;
  const int tileM = blockIdx.x >> 3;
  const int row0 = tileM * 128, col0 = tileN * 512;

  const int lane = tid & 63, w = tid >> 6;
  const int ln15 = lane & 15, quad = lane >> 4;

  // stage A once: wave w stages rows w*16 .. w*16+15 (one 1KB row per DMA)
  #pragma unroll
  for (int i = 0; i < 16; ++i) {
    int r = w * 16 + i;
    int kk = (lane ^ (r & 7)) << 3;          // XOR swizzle on 16B groups
    const unsigned short* gp = Xb + (size_t)(row0 + r) * Dd + kk;
    unsigned short* lp = Ald + r * 512;      // wave-uniform base; +lane*16B by HW
    __builtin_amdgcn_global_load_lds((const GLOBAL_AS void*)gp,
                                     (LDS_AS void*)lp, 16, 0, 0);
  }
  __syncthreads();                           // only barrier in the kernel

  const int colw = col0 + w * 64;
  f32x4 acc[4][8];
  #pragma unroll
  for (int ct = 0; ct < 4; ++ct)
    #pragma unroll
    for (int rt = 0; rt < 8; ++rt) acc[ct][rt] = {0.f, 0.f, 0.f, 0.f};

  const unsigned short* bp[4];
  #pragma unroll
  for (int ct = 0; ct < 4; ++ct)
    bp[ct] = Wb + (size_t)(colw + ct * 16 + ln15) * Dd + quad * 8;

  short8 bc[4];
  #pragma unroll
  for (int ct = 0; ct < 4; ++ct) bc[ct] = *(const short8*)bp[ct];

  for (int ks = 0; ks < 16; ++ks) {
    short8 af[8];
    #pragma unroll
    for (int rt = 0; rt < 8; ++rt) {
      int r = rt * 16 + ln15;
      int phys = (ks * 4 + quad) ^ (r & 7);
      af[rt] = *(const short8*)&Ald[r * 512 + (phys << 3)];
    }
    short8 bn[4];
    int ks2 = (ks < 15) ? (ks + 1) : 15;     // prefetch next k-step's B
    #pragma unroll
    for (int ct = 0; ct < 4; ++ct) bn[ct] = *(const short8*)(bp[ct] + ks2 * 32);
    #pragma unroll
    for (int ct = 0; ct < 4; ++ct)
      #pragma unroll
      for (int rt = 0; rt < 8; ++rt)
        acc[ct][rt] = __builtin_amdgcn_mfma_f32_16x16x32_bf16(af[rt], bc[ct], acc[ct][rt], 0, 0, 0);
    #pragma unroll
    for (int ct = 0; ct < 4; ++ct) bc[ct] = bn[ct];
  }

  // epilogue: row-wise sum over this wave's 64 cols of exp(logit+bias)
  float bv[4];
  #pragma unroll
  for (int ct = 0; ct < 4; ++ct) bv[ct] = bias[colw + ct * 16 + ln15];

  #pragma unroll
  for (int rt = 0; rt < 8; ++rt) {
    #pragma unroll
    for (int r = 0; r < 4; ++r) {
      float s = 0.f;
      #pragma unroll
      for (int ct = 0; ct < 4; ++ct) s += __expf(acc[ct][rt][r] + bv[ct]);
      s += __shfl_xor(s, 1, 64);
      s += __shfl_xor(s, 2, 64);
      s += __shfl_xor(s, 4, 64);
      s += __shfl_xor(s, 8, 64);
      if (ln15 == 0)
        atomicAdd(&Ssum[row0 + rt * 16 + quad * 4 + r], s);
    }
  }
}

// ---- selected-column RAW logits (blank + 30 beams), fp32 ----
// grid: BT/16 blocks, 256 threads. thread = (sel lane 0..31, bt-pair 0..7).
__global__ __launch_bounds__(256) void kB(const float* __restrict__ x,
                                          const float* __restrict__ W,
                                          const float* __restrict__ bias,
                                          const int* __restrict__ beam,
                                          const int* __restrict__ blankp,
                                          float* __restrict__ selL,
                                          int CB) {
  __shared__ float Wlds[31 * 516];
  __shared__ int   selv[32];
  __shared__ float biasv[32];
  const int tid = threadIdx.x;
  const int btbase = blockIdx.x * 16;
  const int b = btbase >> 9;          // 16 | 512 so whole block is one b
  if (tid < 31) {
    int v = (tid == 0) ? *blankp : beam[b * CB + tid - 1];
    selv[tid] = v;
    biasv[tid] = bias[v];
  }
  __syncthreads();
  for (int i = tid; i < 31 * 128; i += 256) {
    int s = i >> 7, c4 = i & 127;
    float4 w4 = *(const float4*)&W[(size_t)selv[s] * Dd + c4 * 4];
    *(float4*)&Wlds[s * 516 + c4 * 4] = w4;
  }
  __syncthreads();
  const int sx = tid & 31, pair = tid >> 5;
  const int kk = (sx < 31) ? sx : 30;
  const int bt0 = btbase + pair * 2, bt1 = bt0 + 1;
  const float4* x40 = (const float4*)&x[(size_t)bt0 * Dd];
  const float4* x41 = (const float4*)&x[(size_t)bt1 * Dd];
  float a0 = 0.f, a1 = 0.f;
  for (int i4 = 0; i4 < 128; ++i4) {
    float4 w4 = *(const float4*)&Wlds[kk * 516 + i4 * 4];
    float4 u = x40[i4];
    float4 v = x41[i4];
    a0 += w4.x * u.x + w4.y * u.y + w4.z * u.z + w4.w * u.w;
    a1 += w4.x * v.x + w4.y * v.y + w4.z * v.z + w4.w * v.w;
  }
  if (sx < 31) {
    selL[(size_t)bt0 * 31 + sx] = a0 + biasv[sx];   // RAW logit (no -log Ssum)
    selL[(size_t)bt1 * 31 + sx] = a1 + biasv[sx];
  }
}

// ---- CTC DP + output assembly. grid: B blocks x 256 threads ----
__global__ __launch_bounds__(256) void kC(const float* __restrict__ selL,
                                          const float* __restrict__ Ssum,
                                          const int* __restrict__ xl,
                                          const int* __restrict__ beam,
                                          const int* __restrict__ blankp,
                                          const int* __restrict__ eosp,
                                          float* __restrict__ out,
                                          int Ly, int CB) {
  __shared__ float sl[Tt * 31];     // 63.5 KB raw selected logits
  __shared__ float lgS[Tt];
  __shared__ float lastP1[Tt];
  __shared__ float blankLp[Tt];
  const int b = blockIdx.x, tid = threadIdx.x;

  for (int i = tid; i < Tt * 31; i += 256) sl[i] = selL[(size_t)b * Tt * 31 + i];
  for (int t = tid; t < Tt; t += 256) lgS[t] = __logf(Ssum[b * Tt + t]);
  __syncthreads();

  float* orow = out + (size_t)b * Vv;
  for (int i = tid; i < Vv; i += 256) orow[i] = LOGZERO;

  const int xlb = xl[b];
  float curP = LOGZERO;
  if (tid < 64) {
    const int lane = tid;
    float vloc[8];
    float run = 0.f;
    #pragma unroll
    for (int u = 0; u < 8; ++u) {
      int t = lane * 8 + u;
      float bl = sl[t * 31] - lgS[t];
      blankLp[t] = bl;
      run += bl;
      vloc[u] = run;
    }
    float inc = run;
    #pragma unroll
    for (int off = 1; off < 64; off <<= 1) {
      float o = __shfl_up(inc, off, 64);
      if (lane >= off) inc += o;
    }
    float excl = inc - run;
    #pragma unroll
    for (int u = 0; u < 8; ++u) lastP1[lane * 8 + u] = vloc[u] + excl;

    const int kk = (lane < CB) ? lane : (CB - 1);
    float Pn = LOGZERO, Pb = LOGZERO;
    float mrun = -3.0e38f, srun = 0.0f;
    int start = (Ly < Tt - 1) ? Ly : (Tt - 1);
    if (start == 0) {
      Pn = sl[1 + kk] - lgS[0];
      float vv = (0 < xlb) ? lgadd(Pn, Pb) : LOGZERO;
      float nm = fmaxf(mrun, vv);
      srun = srun * __expf(mrun - nm) + __expf(vv - nm);
      mrun = nm;
    }
    int t0 = (start > 1) ? start : 1;
    for (int t = t0; t < Tt; ++t) {
      float xn = sl[t * 31 + 1 + kk] - lgS[t];
      float xb = blankLp[t];
      float pref = lastP1[t - 1];   // lastPsum == lastP1 bit-exactly
      float Pn2 = lgadd(Pn, pref) + xn;
      float Pb2 = lgadd(Pn, Pb) + xb;
      Pn = Pn2; Pb = Pb2;
      float vv = (t < xlb) ? lgadd(Pn, Pb) : LOGZERO;
      float nm = fmaxf(mrun, vv);
      srun = srun * __expf(mrun - nm) + __expf(vv - nm);
      mrun = nm;
    }
    curP = mrun + __logf(srun);
  }
  __syncthreads();   // LOGZERO fill + lastP1 complete

  if (tid < 64) {
    if (tid < CB) orow[beam[b * CB + tid]] = curP;
  }
  __syncthreads();
  if (tid == 0) {
    float eosv = (xlb >= 1) ? lastP1[xlb - 1] : 0.0f;
    orow[*eosp] = eosv;
    orow[*blankp] = LOGZERO;
  }
}

extern "C" void kernel_launch(void* const* d_in, const int* in_sizes, int n_in,
                              void* d_out, int out_size, void* d_ws, size_t ws_size,
                              hipStream_t stream) {
  (void)n_in; (void)out_size; (void)ws_size;
  const float* x    = (const float*)d_in[0];
  const float* W    = (const float*)d_in[1];
  const float* bias = (const float*)d_in[2];
  const int* xl     = (const int*)d_in[3];
  const int* beam   = (const int*)d_in[5];
  const int* blankp = (const int*)d_in[6];
  const int* eosp   = (const int*)d_in[7];
  const int Ly = in_sizes[4] / Bb;
  const int CB = in_sizes[5] / Bb;

  float* Ssum = (float*)d_ws;                                        // 64 KB
  float* selL = (float*)((char*)d_ws + (size_t)65536);               // BT*31*4 = 1.94 MB
  unsigned short* Xbf = (unsigned short*)((char*)d_ws + (size_t)2097152);   // 16 MB
  unsigned short* Wbf = (unsigned short*)((char*)d_ws + (size_t)18874368);  // 4 MB
  float* outf = (float*)d_out;

  hipMemsetAsync(Ssum, 0, BT * sizeof(float), stream);
  kConv<<<(BT * Dd + Vv * Dd) / 1024, 256, 0, stream>>>(x, W, Xbf, Wbf);
  kA<<<(BT / 128) * (Vv / 512), 512, 0, stream>>>(Xbf, Wbf, bias, Ssum);
  kB<<<BT / 16, 256, 0, stream>>>(x, W, bias, beam, blankp, selL, CB);
  kC<<<Bb, 256, 0, stream>>>(selL, Ssum, xl, beam, blankp, eosp, outf, Ly, CB);
}

// Round 6
// 366.453 us; speedup vs baseline: 1.1252x; 1.0256x over previous
//
#include <hip/hip_runtime.h>

#define LOGZERO -4290774016.0f   // -(65504^2), exactly representable in fp32

constexpr int Bb = 32, Tt = 512, Dd = 512, Vv = 4096;
constexpr int BT = Bb * Tt;

typedef __attribute__((ext_vector_type(8))) short short8;
typedef __attribute__((ext_vector_type(4))) float f32x4;

#define GLOBAL_AS __attribute__((address_space(1)))
#define LDS_AS    __attribute__((address_space(3)))

__device__ __forceinline__ unsigned short f2bf(float f) {
  unsigned int u = __float_as_uint(f);
  u += 0x7FFFu + ((u >> 16) & 1u);   // RNE
  return (unsigned short)(u >> 16);
}

__device__ __forceinline__ float lgadd(float a, float b) {
  float mx = fmaxf(a, b);
  float d  = fabsf(a - b);
  return mx + __logf(1.0f + __expf(-d));
}

// ---- kPre: W fp32->bf16 + zero Ssum (one dispatch) ----
// grid 2056: blocks 0..2047 convert W (1024 elems each); 2048..2055 zero Ssum.
__global__ __launch_bounds__(256) void kPre(const float* __restrict__ W,
                                            unsigned short* __restrict__ Wb,
                                            float* __restrict__ Ssum) {
  const int blk = blockIdx.x, tid = threadIdx.x;
  if (blk < 2048) {
    size_t i = (size_t)(blk * 256 + tid) * 4;
    float4 v = *(const float4*)(W + i);
    ushort4 h;
    h.x = f2bf(v.x); h.y = f2bf(v.y); h.z = f2bf(v.z); h.w = f2bf(v.w);
    *(ushort4*)(Wb + i) = h;
  } else {
    int idx = (blk - 2048) * 256 + tid;      // 0..2047
    float4 z = {0.f, 0.f, 0.f, 0.f};
    *(float4*)&Ssum[idx * 8] = z;
    *(float4*)&Ssum[idx * 8 + 4] = z;
  }
}

// ---- kMain: mixed-role grid, 512 threads ----
// blocks 0..1023   : GEMM role. Block = 128 rows x 512 cols, full K. A staged
//                    to 128 KB LDS with in-kernel fp32->bf16 cvt (one barrier);
//                    B streamed global->reg, depth-1 prefetch, no K-loop barriers.
//                    tileN = blk&7 pins each 0.5MB B-stripe to one XCD's L2.
// blocks 1024..1535: beam-dot role. 32 bt-rows/block, 31 selected cols, fp32.
__global__ __launch_bounds__(512, 2) void kMain(const float* __restrict__ x,
                                                const float* __restrict__ W,
                                                const unsigned short* __restrict__ Wb,
                                                const float* __restrict__ bias,
                                                const int* __restrict__ beam,
                                                const int* __restrict__ blankp,
                                                float* __restrict__ Ssum,
                                                float* __restrict__ selL,
                                                int CB) {
  __shared__ char ldsraw[128 * 512 * 2];     // 128 KB union
  const int tid = threadIdx.x;
  const int blk = blockIdx.x;

  if (blk < 1024) {
    // ================= GEMM + exp-sum role =================
    unsigned short* Ald = (unsigned short*)ldsraw;
    const int tileN = blk & 7;
    const int tileM = blk >> 3;
    const int row0 = tileM * 128, col0 = tileN * 512;

    const int lane = tid & 63, w = tid >> 6;
    const int ln15 = lane & 15, quad = lane >> 4;

    // stage A: convert 128x512 fp32 -> bf16 into swizzled LDS
    const float* xp = x + (size_t)row0 * Dd;
    #pragma unroll
    for (int i = 0; i < 16; ++i) {
      int G = tid + i * 512;                 // 16-B group id, 0..8191
      int r = G >> 6, gi = G & 63;
      const float* src = xp + (size_t)r * Dd + gi * 8;
      float4 v0 = *(const float4*)src;
      float4 v1 = *(const float4*)(src + 4);
      short8 h;
      h[0] = (short)f2bf(v0.x); h[1] = (short)f2bf(v0.y);
      h[2] = (short)f2bf(v0.z); h[3] = (short)f2bf(v0.w);
      h[4] = (short)f2bf(v1.x); h[5] = (short)f2bf(v1.y);
      h[6] = (short)f2bf(v1.z); h[7] = (short)f2bf(v1.w);
      int off = r * 512 + ((gi ^ (r & 7)) << 3);
      *(short8*)&Ald[off] = h;
    }
    __syncthreads();                         // only barrier in this role

    const int colw = col0 + w * 64;
    f32x4 acc[4][8];
    #pragma unroll
    for (int ct = 0; ct < 4; ++ct)
      #pragma unroll
      for (int rt = 0; rt < 8; ++rt) acc[ct][rt] = {0.f, 0.f, 0.f, 0.f};

    const unsigned short* bp[4];
    #pragma unroll
    for (int ct = 0; ct < 4; ++ct)
      bp[ct] = Wb + (size_t)(colw + ct * 16 + ln15) * Dd + quad * 8;

    short8 bc[4];
    #pragma unroll
    for (int ct = 0; ct < 4; ++ct) bc[ct] = *(const short8*)bp[ct];

    for (int ks = 0; ks < 16; ++ks) {
      short8 af[8];
      #pragma unroll
      for (int rt = 0; rt < 8; ++rt) {
        int r = rt * 16 + ln15;
        int phys = (ks * 4 + quad) ^ (r & 7);
        af[rt] = *(const short8*)&Ald[r * 512 + (phys << 3)];
      }
      short8 bn[4];
      int ks2 = (ks < 15) ? (ks + 1) : 15;   // depth-1 B prefetch
      #pragma unroll
      for (int ct = 0; ct < 4; ++ct) bn[ct] = *(const short8*)(bp[ct] + ks2 * 32);
      #pragma unroll
      for (int ct = 0; ct < 4; ++ct)
        #pragma unroll
        for (int rt = 0; rt < 8; ++rt)
          acc[ct][rt] = __builtin_amdgcn_mfma_f32_16x16x32_bf16(af[rt], bc[ct], acc[ct][rt], 0, 0, 0);
      #pragma unroll
      for (int ct = 0; ct < 4; ++ct) bc[ct] = bn[ct];
    }

    // epilogue: row-wise sum(exp(logit+bias)) over this wave's 64 cols
    float bv[4];
    #pragma unroll
    for (int ct = 0; ct < 4; ++ct) bv[ct] = bias[colw + ct * 16 + ln15];

    #pragma unroll
    for (int rt = 0; rt < 8; ++rt) {
      #pragma unroll
      for (int r = 0; r < 4; ++r) {
        float s = 0.f;
        #pragma unroll
        for (int ct = 0; ct < 4; ++ct) s += __expf(acc[ct][rt][r] + bv[ct]);
        s += __shfl_xor(s, 1, 64);
        s += __shfl_xor(s, 2, 64);
        s += __shfl_xor(s, 4, 64);
        s += __shfl_xor(s, 8, 64);
        if (ln15 == 0)
          atomicAdd(&Ssum[row0 + rt * 16 + quad * 4 + r], s);
      }
    }
  } else {
    // ================= beam-dot role (raw logits, fp32) =================
    float* Wlds = (float*)ldsraw;            // 31*516 floats = 64 KB
    __shared__ int   selv[32];
    __shared__ float biasv[32];
    const int btbase = (blk - 1024) * 32;
    const int b = btbase >> 9;               // 32 | 512 so whole block is one b
    if (tid < 31) {
      int v = (tid == 0) ? *blankp : beam[b * CB + tid - 1];
      selv[tid] = v;
      biasv[tid] = bias[v];
    }
    __syncthreads();
    for (int i = tid; i < 31 * 128; i += 512) {
      int s = i >> 7, c4 = i & 127;
      float4 w4 = *(const float4*)&W[(size_t)selv[s] * Dd + c4 * 4];
      *(float4*)&Wlds[s * 516 + c4 * 4] = w4;
    }
    __syncthreads();
    const int sx = tid & 31, pair = tid >> 5;      // pair 0..15
    const int kk = (sx < 31) ? sx : 30;
    const int bt0 = btbase + pair * 2, bt1 = bt0 + 1;
    const float4* x40 = (const float4*)&x[(size_t)bt0 * Dd];
    const float4* x41 = (const float4*)&x[(size_t)bt1 * Dd];
    float a0 = 0.f, a1 = 0.f;
    for (int i4 = 0; i4 < 128; ++i4) {
      float4 w4 = *(const float4*)&Wlds[kk * 516 + i4 * 4];
      float4 u = x40[i4];
      float4 v = x41[i4];
      a0 += w4.x * u.x + w4.y * u.y + w4.z * u.z + w4.w * u.w;
      a1 += w4.x * v.x + w4.y * v.y + w4.z * v.z + w4.w * v.w;
    }
    if (sx < 31) {
      selL[(size_t)bt0 * 31 + sx] = a0 + biasv[sx];   // RAW logit
      selL[(size_t)bt1 * 31 + sx] = a1 + biasv[sx];
    }
  }
}

// ---- CTC DP + output assembly. grid: B blocks x 256 threads ----
__global__ __launch_bounds__(256) void kC(const float* __restrict__ selL,
                                          const float* __restrict__ Ssum,
                                          const int* __restrict__ xl,
                                          const int* __restrict__ beam,
                                          const int* __restrict__ blankp,
                                          const int* __restrict__ eosp,
                                          float* __restrict__ out,
                                          int Ly, int CB) {
  __shared__ float sl[Tt * 31];     // 63.5 KB raw selected logits
  __shared__ float lgS[Tt];
  __shared__ float lastP1[Tt];
  __shared__ float blankLp[Tt];
  const int b = blockIdx.x, tid = threadIdx.x;

  for (int i = tid; i < Tt * 31; i += 256) sl[i] = selL[(size_t)b * Tt * 31 + i];
  for (int t = tid; t < Tt; t += 256) lgS[t] = __logf(Ssum[b * Tt + t]);
  __syncthreads();

  float* orow = out + (size_t)b * Vv;
  for (int i = tid; i < Vv; i += 256) orow[i] = LOGZERO;

  const int xlb = xl[b];
  float curP = LOGZERO;
  if (tid < 64) {
    const int lane = tid;
    float vloc[8];
    float run = 0.f;
    #pragma unroll
    for (int u = 0; u < 8; ++u) {
      int t = lane * 8 + u;
      float bl = sl[t * 31] - lgS[t];
      blankLp[t] = bl;
      run += bl;
      vloc[u] = run;
    }
    float inc = run;
    #pragma unroll
    for (int off = 1; off < 64; off <<= 1) {
      float o = __shfl_up(inc, off, 64);
      if (lane >= off) inc += o;
    }
    float excl = inc - run;
    #pragma unroll
    for (int u = 0; u < 8; ++u) lastP1[lane * 8 + u] = vloc[u] + excl;

    const int kk = (lane < CB) ? lane : (CB - 1);
    float Pn = LOGZERO, Pb = LOGZERO;
    float mrun = -3.0e38f, srun = 0.0f;
    int start = (Ly < Tt - 1) ? Ly : (Tt - 1);
    if (start == 0) {
      Pn = sl[1 + kk] - lgS[0];
      float vv = (0 < xlb) ? lgadd(Pn, Pb) : LOGZERO;
      float nm = fmaxf(mrun, vv);
      srun = srun * __expf(mrun - nm) + __expf(vv - nm);
      mrun = nm;
    }
    int t0 = (start > 1) ? start : 1;
    for (int t = t0; t < Tt; ++t) {
      float xn = sl[t * 31 + 1 + kk] - lgS[t];
      float xb = blankLp[t];
      float pref = lastP1[t - 1];   // lastPsum == lastP1 bit-exactly
      float Pn2 = lgadd(Pn, pref) + xn;
      float Pb2 = lgadd(Pn, Pb) + xb;
      Pn = Pn2; Pb = Pb2;
      float vv = (t < xlb) ? lgadd(Pn, Pb) : LOGZERO;
      float nm = fmaxf(mrun, vv);
      srun = srun * __expf(mrun - nm) + __expf(vv - nm);
      mrun = nm;
    }
    curP = mrun + __logf(srun);
  }
  __syncthreads();   // LOGZERO fill + lastP1 complete

  if (tid < 64) {
    if (tid < CB) orow[beam[b * CB + tid]] = curP;
  }
  __syncthreads();
  if (tid == 0) {
    float eosv = (xlb >= 1) ? lastP1[xlb - 1] : 0.0f;
    orow[*eosp] = eosv;
    orow[*blankp] = LOGZERO;
  }
}

extern "C" void kernel_launch(void* const* d_in, const int* in_sizes, int n_in,
                              void* d_out, int out_size, void* d_ws, size_t ws_size,
                              hipStream_t stream) {
  (void)n_in; (void)out_size; (void)ws_size;
  const float* x    = (const float*)d_in[0];
  const float* W    = (const float*)d_in[1];
  const float* bias = (const float*)d_in[2];
  const int* xl     = (const int*)d_in[3];
  const int* beam   = (const int*)d_in[5];
  const int* blankp = (const int*)d_in[6];
  const int* eosp   = (const int*)d_in[7];
  const int Ly = in_sizes[4] / Bb;
  const int CB = in_sizes[5] / Bb;

  float* Ssum = (float*)d_ws;                                        // 64 KB
  float* selL = (float*)((char*)d_ws + (size_t)65536);               // BT*31*4 = 1.94 MB
  unsigned short* Wbf = (unsigned short*)((char*)d_ws + (size_t)2097152);  // 4 MB
  float* outf = (float*)d_out;

  kPre<<<2056, 256, 0, stream>>>(W, Wbf, Ssum);
  kMain<<<1536, 512, 0, stream>>>(x, W, Wbf, bias, beam, blankp, Ssum, selL, CB);
  kC<<<Bb, 256, 0, stream>>>(selL, Ssum, xl, beam, blankp, eosp, outf, Ly, CB);
}

// Round 8
// 284.980 us; speedup vs baseline: 1.4469x; 1.2859x over previous
//
#include <hip/hip_runtime.h>

#define LOGZERO -4290774016.0f   // -(65504^2), exactly representable in fp32
#define L2E 1.4426950408889634f  // log2(e)
#define LN2 0.6931471805599453f

constexpr int Bb = 32, Tt = 512, Dd = 512, Vv = 4096;
constexpr int BT = Bb * Tt;

typedef __attribute__((ext_vector_type(8))) short short8;
typedef __attribute__((ext_vector_type(4))) float f32x4;

#define GLOBAL_AS __attribute__((address_space(1)))
#define LDS_AS    __attribute__((address_space(3)))

__device__ __forceinline__ float fexp2(float x) { return __builtin_amdgcn_exp2f(x); }  // v_exp_f32: 2^x
__device__ __forceinline__ float flog2(float x) { return __builtin_amdgcn_logf(x); }   // v_log_f32: log2(x)

__device__ __forceinline__ unsigned short f2bf(float f) {
  unsigned int u = __float_as_uint(f);
  u += 0x7FFFu + ((u >> 16) & 1u);   // RNE
  return (unsigned short)(u >> 16);
}

// logaddexp in the log2 domain: native v_exp_f32 / v_log_f32, no fixup muls
__device__ __forceinline__ float lg2add(float a, float b) {
  float mx = fmaxf(a, b);
  float d  = fabsf(a - b);
  return mx + flog2(1.0f + fexp2(-d));
}

// ---- kPre: x fp32->bf16, W fp32->bf16, zero Ssum — one dispatch ----
// blocks 0..8191: x (1024 floats each); 8192..10239: W; 10240..10247: Ssum.
__global__ __launch_bounds__(256) void kPre(const float* __restrict__ x,
                                            const float* __restrict__ W,
                                            unsigned short* __restrict__ Xb,
                                            unsigned short* __restrict__ Wb,
                                            float* __restrict__ Ssum) {
  const int blk = blockIdx.x, tid = threadIdx.x;
  if (blk < 8192) {
    size_t i = (size_t)(blk * 256 + tid) * 4;
    float4 v = *(const float4*)(x + i);
    ushort4 h;
    h.x = f2bf(v.x); h.y = f2bf(v.y); h.z = f2bf(v.z); h.w = f2bf(v.w);
    *(ushort4*)(Xb + i) = h;
  } else if (blk < 10240) {
    size_t i = (size_t)((blk - 8192) * 256 + tid) * 4;
    float4 v = *(const float4*)(W + i);
    ushort4 h;
    h.x = f2bf(v.x); h.y = f2bf(v.y); h.z = f2bf(v.z); h.w = f2bf(v.w);
    *(ushort4*)(Wb + i) = h;
  } else {
    int idx = (blk - 10240) * 256 + tid;     // 0..2047
    float4 z = {0.f, 0.f, 0.f, 0.f};
    *(float4*)&Ssum[idx * 8] = z;
    *(float4*)&Ssum[idx * 8 + 4] = z;
  }
}

// ---- barrier-free GEMM + fused exp-sum + beam-logit scatter, M_tile=128 ----
// Block = 128 rows x 512 cols, full K=512. A resident in 128 KB LDS (staged
// once via DMA, one barrier); B streamed global->reg, depth-1 prefetch.
// grid 1024: tileN = blk&7 pins each 0.5MB B-stripe to one XCD's L2.
__global__ __launch_bounds__(512, 2) void kA(const unsigned short* __restrict__ Xb,
                                             const unsigned short* __restrict__ Wb,
                                             const float* __restrict__ bias,
                                             const int* __restrict__ beam,
                                             const int* __restrict__ blankp,
                                             float* __restrict__ Ssum,
                                             float* __restrict__ selL,
                                             int CB) {
  __shared__ unsigned short Ald[128 * 512];   // 128 KB, xor-swizzled 16B groups
  __shared__ int   selv[31];
  __shared__ float selb[31];
  const int tid = threadIdx.x;
  const int tileN = blockIdx.x & 7;
  const int tileM = blockIdx.x >> 3;
  const int row0 = tileM * 128, col0 = tileN * 512;
  const int b = row0 >> 9;                   // 128 | 512: one batch per block

  if (tid < 31) {
    int v = (tid == 0) ? *blankp : beam[b * CB + tid - 1];
    selv[tid] = v;
    selb[tid] = bias[v];
  }

  const int lane = tid & 63, w = tid >> 6;
  const int ln15 = lane & 15, quad = lane >> 4;

  // stage A once: wave w stages rows w*16 .. w*16+15 (one 1KB row per DMA)
  #pragma unroll
  for (int i = 0; i < 16; ++i) {
    int r = w * 16 + i;
    int kk = (lane ^ (r & 7)) << 3;          // XOR swizzle on 16B groups
    const unsigned short* gp = Xb + (size_t)(row0 + r) * Dd + kk;
    unsigned short* lp = Ald + r * 512;      // wave-uniform base; +lane*16B by HW
    __builtin_amdgcn_global_load_lds((const GLOBAL_AS void*)gp,
                                     (LDS_AS void*)lp, 16, 0, 0);
  }
  __syncthreads();                           // only barrier in the kernel

  const int colw = col0 + w * 64;
  f32x4 acc[4][8];
  #pragma unroll
  for (int ct = 0; ct < 4; ++ct)
    #pragma unroll
    for (int rt = 0; rt < 8; ++rt) acc[ct][rt] = {0.f, 0.f, 0.f, 0.f};

  const unsigned short* bp[4];
  #pragma unroll
  for (int ct = 0; ct < 4; ++ct)
    bp[ct] = Wb + (size_t)(colw + ct * 16 + ln15) * Dd + quad * 8;

  short8 bc[4];
  #pragma unroll
  for (int ct = 0; ct < 4; ++ct) bc[ct] = *(const short8*)bp[ct];

  for (int ks = 0; ks < 16; ++ks) {
    short8 af[8];
    #pragma unroll
    for (int rt = 0; rt < 8; ++rt) {
      int r = rt * 16 + ln15;
      int phys = (ks * 4 + quad) ^ (r & 7);
      af[rt] = *(const short8*)&Ald[r * 512 + (phys << 3)];
    }
    short8 bn[4];
    int ks2 = (ks < 15) ? (ks + 1) : 15;     // depth-1 B prefetch
    #pragma unroll
    for (int ct = 0; ct < 4; ++ct) bn[ct] = *(const short8*)(bp[ct] + ks2 * 32);
    #pragma unroll
    for (int ct = 0; ct < 4; ++ct)
      #pragma unroll
      for (int rt = 0; rt < 8; ++rt)
        acc[ct][rt] = __builtin_amdgcn_mfma_f32_16x16x32_bf16(af[rt], bc[ct], acc[ct][rt], 0, 0, 0);
    #pragma unroll
    for (int ct = 0; ct < 4; ++ct) bc[ct] = bn[ct];
  }

  // epilogue 1: row-wise sum(exp(logit+bias)) over this wave's 64 cols
  // exp(z) = 2^(z*log2e): one mul + native v_exp_f32
  float bv[4];
  #pragma unroll
  for (int ct = 0; ct < 4; ++ct) bv[ct] = bias[colw + ct * 16 + ln15];

  #pragma unroll
  for (int rt = 0; rt < 8; ++rt) {
    #pragma unroll
    for (int r = 0; r < 4; ++r) {
      float s = 0.f;
      #pragma unroll
      for (int ct = 0; ct < 4; ++ct) s += fexp2((acc[ct][rt][r] + bv[ct]) * L2E);
      s += __shfl_xor(s, 1, 64);
      s += __shfl_xor(s, 2, 64);
      s += __shfl_xor(s, 4, 64);
      s += __shfl_xor(s, 8, 64);
      if (ln15 == 0)
        atomicAdd(&Ssum[row0 + rt * 16 + quad * 4 + r], s);
    }
  }

  // epilogue 2: beam-column scatter (raw logit + bias); all acc indices
  // compile-time via guarded unroll — no scratch demotion.
  const int tbase = row0 & 511;
  #pragma unroll
  for (int ct = 0; ct < 4; ++ct) {
    for (int s = 0; s < 31; ++s) {
      int local = selv[s] - colw - ct * 16;
      if (local >= 0 && local < 16 && ln15 == local) {
        float bvs = selb[s];
        #pragma unroll
        for (int rt = 0; rt < 8; ++rt)
          #pragma unroll
          for (int r = 0; r < 4; ++r) {
            int t = tbase + rt * 16 + quad * 4 + r;
            selL[((size_t)b * Tt + t) * 31 + s] = acc[ct][rt][r] + bvs;
          }
      }
    }
  }
}

// ---- CTC DP + output assembly, log2 domain. grid: B blocks x 256 threads ----
__global__ __launch_bounds__(256) void kC(const float* __restrict__ selL,
                                          const float* __restrict__ Ssum,
                                          const int* __restrict__ xl,
                                          const int* __restrict__ beam,
                                          const int* __restrict__ blankp,
                                          const int* __restrict__ eosp,
                                          float* __restrict__ out,
                                          int Ly, int CB) {
  __shared__ float sl[Tt * 31];     // raw logits * log2(e)
  __shared__ float lgS[Tt];         // log2(Ssum)
  __shared__ float lastP1[Tt];      // log2-domain blank cumsum
  __shared__ float blankLp[Tt];     // log2-domain blank logp
  const int b = blockIdx.x, tid = threadIdx.x;

  for (int i = tid; i < Tt * 31; i += 256)
    sl[i] = selL[(size_t)b * Tt * 31 + i] * L2E;
  for (int t = tid; t < Tt; t += 256) lgS[t] = flog2(Ssum[b * Tt + t]);
  __syncthreads();

  float* orow = out + (size_t)b * Vv;
  for (int i = tid; i < Vv; i += 256) orow[i] = LOGZERO;

  const int xlb = xl[b];
  float curP = LOGZERO;
  if (tid < 64) {
    const int lane = tid;
    float vloc[8];
    float run = 0.f;
    #pragma unroll
    for (int u = 0; u < 8; ++u) {
      int t = lane * 8 + u;
      float bl = sl[t * 31] - lgS[t];
      blankLp[t] = bl;
      run += bl;
      vloc[u] = run;
    }
    float inc = run;
    #pragma unroll
    for (int off = 1; off < 64; off <<= 1) {
      float o = __shfl_up(inc, off, 64);
      if (lane >= off) inc += o;
    }
    float excl = inc - run;
    #pragma unroll
    for (int u = 0; u < 8; ++u) lastP1[lane * 8 + u] = vloc[u] + excl;

    const int kk = (lane < CB) ? lane : (CB - 1);
    const float LOG2ZERO = LOGZERO * L2E;
    float Pn = LOG2ZERO, Pb = LOG2ZERO;
    float mrun = -3.0e38f, srun = 0.0f;
    int start = (Ly < Tt - 1) ? Ly : (Tt - 1);
    if (start == 0) {
      Pn = sl[1 + kk] - lgS[0];
      float vv = (0 < xlb) ? lg2add(Pn, Pb) : LOG2ZERO;
      float nm = fmaxf(mrun, vv);
      srun = srun * fexp2(mrun - nm) + fexp2(vv - nm);
      mrun = nm;
    }
    int t0 = (start > 1) ? start : 1;
    #pragma unroll 2
    for (int t = t0; t < Tt; ++t) {
      float xn = sl[t * 31 + 1 + kk] - lgS[t];
      float xb = blankLp[t];
      float pref = lastP1[t - 1];   // lastPsum == lastP1 bit-exactly
      float Pn2 = lg2add(Pn, pref) + xn;
      float Pb2 = lg2add(Pn, Pb) + xb;
      Pn = Pn2; Pb = Pb2;
      float vv = (t < xlb) ? lg2add(Pn, Pb) : LOG2ZERO;   // off critical path
      float nm = fmaxf(mrun, vv);
      srun = srun * fexp2(mrun - nm) + fexp2(vv - nm);
      mrun = nm;
    }
    curP = (mrun + flog2(srun)) * LN2;       // back to ln domain
  }
  __syncthreads();   // LOGZERO fill + lastP1 complete

  if (tid < 64) {
    if (tid < CB) orow[beam[b * CB + tid]] = curP;
  }
  __syncthreads();
  if (tid == 0) {
    float eosv = (xlb >= 1) ? lastP1[xlb - 1] * LN2 : 0.0f;
    orow[*eosp] = eosv;
    orow[*blankp] = LOGZERO;
  }
}

extern "C" void kernel_launch(void* const* d_in, const int* in_sizes, int n_in,
                              void* d_out, int out_size, void* d_ws, size_t ws_size,
                              hipStream_t stream) {
  (void)n_in; (void)out_size; (void)ws_size;
  const float* x    = (const float*)d_in[0];
  const float* W    = (const float*)d_in[1];
  const float* bias = (const float*)d_in[2];
  const int* xl     = (const int*)d_in[3];
  const int* beam   = (const int*)d_in[5];
  const int* blankp = (const int*)d_in[6];
  const int* eosp   = (const int*)d_in[7];
  const int Ly = in_sizes[4] / Bb;
  const int CB = in_sizes[5] / Bb;

  float* Ssum = (float*)d_ws;                                        // 64 KB
  float* selL = (float*)((char*)d_ws + (size_t)65536);               // 1.94 MB
  unsigned short* Xbf = (unsigned short*)((char*)d_ws + (size_t)2097152);   // 16 MB
  unsigned short* Wbf = (unsigned short*)((char*)d_ws + (size_t)18874368);  // 4 MB
  float* outf = (float*)d_out;

  kPre<<<10248, 256, 0, stream>>>(x, W, Xbf, Wbf, Ssum);
  kA<<<(BT / 128) * (Vv / 512), 512, 0, stream>>>(Xbf, Wbf, bias, beam, blankp, Ssum, selL, CB);
  kC<<<Bb, 256, 0, stream>>>(selL, Ssum, xl, beam, blankp, eosp, outf, Ly, CB);
}

// Round 9
// 275.924 us; speedup vs baseline: 1.4944x; 1.0328x over previous
//
#include <hip/hip_runtime.h>
#include <hip/hip_fp8.h>

#define LOGZERO -4290774016.0f   // -(65504^2), exactly representable in fp32
#define L2E 1.4426950408889634f  // log2(e)
#define LN2 0.6931471805599453f

constexpr int Bb = 32, Tt = 512, Dd = 512, Vv = 4096;
constexpr int BT = Bb * Tt;

typedef __attribute__((ext_vector_type(4))) float f32x4;
typedef long i64;

#define GLOBAL_AS __attribute__((address_space(1)))
#define LDS_AS    __attribute__((address_space(3)))

__device__ __forceinline__ float fexp2(float x) { return __builtin_amdgcn_exp2f(x); }  // v_exp_f32: 2^x
__device__ __forceinline__ float flog2(float x) { return __builtin_amdgcn_logf(x); }   // v_log_f32: log2(x)

// pack 4 floats (scaled) -> 4 OCP e4m3 bytes
__device__ __forceinline__ unsigned cvt4_fp8(float4 v, float s) {
#if __has_builtin(__builtin_amdgcn_cvt_pk_fp8_f32)
  int p = __builtin_amdgcn_cvt_pk_fp8_f32(v.x * s, v.y * s, 0, false);
  p = __builtin_amdgcn_cvt_pk_fp8_f32(v.z * s, v.w * s, p, true);
  return (unsigned)p;
#else
  unsigned b0 = __hip_cvt_float_to_fp8(v.x * s, __HIP_SATFINITE, __HIP_E4M3);
  unsigned b1 = __hip_cvt_float_to_fp8(v.y * s, __HIP_SATFINITE, __HIP_E4M3);
  unsigned b2 = __hip_cvt_float_to_fp8(v.z * s, __HIP_SATFINITE, __HIP_E4M3);
  unsigned b3 = __hip_cvt_float_to_fp8(v.w * s, __HIP_SATFINITE, __HIP_E4M3);
  return b0 | (b1 << 8) | (b2 << 16) | (b3 << 24);
#endif
}

// logaddexp in the log2 domain
__device__ __forceinline__ float lg2add(float a, float b) {
  float mx = fmaxf(a, b);
  float d  = fabsf(a - b);
  return mx + flog2(1.0f + fexp2(-d));
}

// ---- kPre: x -> fp8 (x1), W -> fp8 (x16 prescale), zero Ssum ----
// blocks 0..2047: x (16 elems/thread); 2048..2559: W; 2560..2567: Ssum.
__global__ __launch_bounds__(256) void kPre(const float* __restrict__ x,
                                            const float* __restrict__ W,
                                            unsigned char* __restrict__ Xf,
                                            unsigned char* __restrict__ Wf,
                                            float* __restrict__ Ssum) {
  const int blk = blockIdx.x, tid = threadIdx.x;
  if (blk < 2048) {
    size_t i = ((size_t)blk * 256 + tid) * 16;
    uint4 o;
    o.x = cvt4_fp8(*(const float4*)(x + i), 1.0f);
    o.y = cvt4_fp8(*(const float4*)(x + i + 4), 1.0f);
    o.z = cvt4_fp8(*(const float4*)(x + i + 8), 1.0f);
    o.w = cvt4_fp8(*(const float4*)(x + i + 12), 1.0f);
    *(uint4*)(Xf + i) = o;
  } else if (blk < 2560) {
    size_t i = ((size_t)(blk - 2048) * 256 + tid) * 16;
    uint4 o;
    o.x = cvt4_fp8(*(const float4*)(W + i), 16.0f);     // x16: into e4m3 normal range
    o.y = cvt4_fp8(*(const float4*)(W + i + 4), 16.0f);
    o.z = cvt4_fp8(*(const float4*)(W + i + 8), 16.0f);
    o.w = cvt4_fp8(*(const float4*)(W + i + 12), 16.0f);
    *(uint4*)(Wf + i) = o;
  } else {
    int idx = (blk - 2560) * 256 + tid;     // 0..2047
    float4 z = {0.f, 0.f, 0.f, 0.f};
    *(float4*)&Ssum[idx * 8] = z;
    *(float4*)&Ssum[idx * 8 + 4] = z;
  }
}

// ---- barrier-free fp8 GEMM + fused exp-sum + beam scatter ----
// Block = 128 rows x 256 cols, full K=512, 256 threads (4 waves, each 128x64).
// A tile = 64 KB fp8 LDS (staged once via DMA) -> 2 blocks/CU. B streamed
// global->reg (8 B/frag), depth-1 prefetch, zero K-loop barriers.
// grid 2048: tileN = blk&15 -> each XCD's two B-stripes = 0.5 MB, L2-resident.
__global__ __launch_bounds__(256, 2) void kA(const unsigned char* __restrict__ Xf,
                                             const unsigned char* __restrict__ Wf,
                                             const float* __restrict__ bias,
                                             const int* __restrict__ beam,
                                             const int* __restrict__ blankp,
                                             float* __restrict__ Ssum,
                                             float* __restrict__ selL,
                                             int CB) {
  __shared__ unsigned char Ald[128 * 512];   // 64 KB, xor-swizzled 16B groups
  __shared__ int   selv[31];
  __shared__ float selb[31];
  const int tid = threadIdx.x;
  const int tileN = blockIdx.x & 15;
  const int tileM = blockIdx.x >> 4;
  const int row0 = tileM * 128, col0 = tileN * 256;
  const int b = row0 >> 9;                   // 128 | 512: one batch per block

  if (tid < 31) {
    int v = (tid == 0) ? *blankp : beam[b * CB + tid - 1];
    selv[tid] = v;
    selb[tid] = bias[v];
  }

  const int lane = tid & 63, w = tid >> 6;
  const int ln15 = lane & 15, quad = lane >> 4;

  // stage A once: wave w stages rows w*32..w*32+31; one DMA = 2 rows (512 B each)
  #pragma unroll
  for (int i = 0; i < 16; ++i) {
    int rp = w * 32 + i * 2;
    int r = rp + (lane >> 5);
    int g = (lane & 31) ^ (r & 7);           // read swizzled source so LDS lands swizzled
    const unsigned char* gp = Xf + (size_t)(row0 + r) * 512 + g * 16;
    unsigned char* lp = Ald + rp * 512;      // wave-uniform base; +lane*16B by HW
    __builtin_amdgcn_global_load_lds((const GLOBAL_AS void*)gp,
                                     (LDS_AS void*)lp, 16, 0, 0);
  }
  __syncthreads();                           // only barrier in the kernel

  const int colw = col0 + w * 64;
  f32x4 acc[4][8];
  #pragma unroll
  for (int ct = 0; ct < 4; ++ct)
    #pragma unroll
    for (int rt = 0; rt < 8; ++rt) acc[ct][rt] = {0.f, 0.f, 0.f, 0.f};

  const unsigned char* bp[4];
  #pragma unroll
  for (int ct = 0; ct < 4; ++ct)
    bp[ct] = Wf + (size_t)(colw + ct * 16 + ln15) * 512 + quad * 8;

  i64 bc[4];
  #pragma unroll
  for (int ct = 0; ct < 4; ++ct) bc[ct] = *(const i64*)bp[ct];

  for (int ks = 0; ks < 16; ++ks) {
    i64 af[8];
    #pragma unroll
    for (int rt = 0; rt < 8; ++rt) {
      int r = rt * 16 + ln15;
      int g = (ks * 2 + (quad >> 1)) ^ (r & 7);
      af[rt] = *(const i64*)&Ald[r * 512 + g * 16 + (quad & 1) * 8];
    }
    i64 bn[4];
    int ks2 = (ks < 15) ? (ks + 1) : 15;     // depth-1 B prefetch
    #pragma unroll
    for (int ct = 0; ct < 4; ++ct) bn[ct] = *(const i64*)(bp[ct] + ks2 * 32);
    #pragma unroll
    for (int ct = 0; ct < 4; ++ct)
      #pragma unroll
      for (int rt = 0; rt < 8; ++rt)
        acc[ct][rt] = __builtin_amdgcn_mfma_f32_16x16x32_fp8_fp8(af[rt], bc[ct], acc[ct][rt], 0, 0, 0);
    #pragma unroll
    for (int ct = 0; ct < 4; ++ct) bc[ct] = bn[ct];
  }

  // epilogue 1: row-wise sum(exp(logit+bias)); logit = acc/16 (undo W prescale)
  float bvl[4];
  #pragma unroll
  for (int ct = 0; ct < 4; ++ct) bvl[ct] = bias[colw + ct * 16 + ln15] * L2E;
  const float SC = 0.0625f * L2E;

  #pragma unroll
  for (int rt = 0; rt < 8; ++rt) {
    #pragma unroll
    for (int r = 0; r < 4; ++r) {
      float s = 0.f;
      #pragma unroll
      for (int ct = 0; ct < 4; ++ct) s += fexp2(acc[ct][rt][r] * SC + bvl[ct]);
      s += __shfl_xor(s, 1, 64);
      s += __shfl_xor(s, 2, 64);
      s += __shfl_xor(s, 4, 64);
      s += __shfl_xor(s, 8, 64);
      if (ln15 == 0)
        atomicAdd(&Ssum[row0 + rt * 16 + quad * 4 + r], s);
    }
  }

  // epilogue 2: beam-column scatter (raw ln-domain logit + bias)
  const int tbase = row0 & 511;
  #pragma unroll
  for (int ct = 0; ct < 4; ++ct) {
    for (int s = 0; s < 31; ++s) {
      int local = selv[s] - colw - ct * 16;
      if (local >= 0 && local < 16 && ln15 == local) {
        float bvs = selb[s];
        #pragma unroll
        for (int rt = 0; rt < 8; ++rt)
          #pragma unroll
          for (int r = 0; r < 4; ++r) {
            int t = tbase + rt * 16 + quad * 4 + r;
            selL[((size_t)b * Tt + t) * 31 + s] = acc[ct][rt][r] * 0.0625f + bvs;
          }
      }
    }
  }
}

// ---- CTC DP + output assembly, log2 domain. grid: B blocks x 256 threads ----
__global__ __launch_bounds__(256) void kC(const float* __restrict__ selL,
                                          const float* __restrict__ Ssum,
                                          const int* __restrict__ xl,
                                          const int* __restrict__ beam,
                                          const int* __restrict__ blankp,
                                          const int* __restrict__ eosp,
                                          float* __restrict__ out,
                                          int Ly, int CB) {
  __shared__ float sl[Tt * 31];     // raw logits * log2(e)
  __shared__ float lgS[Tt];         // log2(Ssum)
  __shared__ float lastP1[Tt];      // log2-domain blank cumsum
  __shared__ float blankLp[Tt];     // log2-domain blank logp
  const int b = blockIdx.x, tid = threadIdx.x;

  for (int i = tid; i < Tt * 31; i += 256)
    sl[i] = selL[(size_t)b * Tt * 31 + i] * L2E;
  for (int t = tid; t < Tt; t += 256) lgS[t] = flog2(Ssum[b * Tt + t]);
  __syncthreads();

  float* orow = out + (size_t)b * Vv;
  for (int i = tid; i < Vv; i += 256) orow[i] = LOGZERO;

  const int xlb = xl[b];
  float curP = LOGZERO;
  if (tid < 64) {
    const int lane = tid;
    float vloc[8];
    float run = 0.f;
    #pragma unroll
    for (int u = 0; u < 8; ++u) {
      int t = lane * 8 + u;
      float bl = sl[t * 31] - lgS[t];
      blankLp[t] = bl;
      run += bl;
      vloc[u] = run;
    }
    float inc = run;
    #pragma unroll
    for (int off = 1; off < 64; off <<= 1) {
      float o = __shfl_up(inc, off, 64);
      if (lane >= off) inc += o;
    }
    float excl = inc - run;
    #pragma unroll
    for (int u = 0; u < 8; ++u) lastP1[lane * 8 + u] = vloc[u] + excl;

    const int kk = (lane < CB) ? lane : (CB - 1);
    const float LOG2ZERO = LOGZERO * L2E;
    float Pn = LOG2ZERO, Pb = LOG2ZERO;
    float mrun = -3.0e38f, srun = 0.0f;
    int start = (Ly < Tt - 1) ? Ly : (Tt - 1);
    if (start == 0) {
      Pn = sl[1 + kk] - lgS[0];
      float vv = (0 < xlb) ? lg2add(Pn, Pb) : LOG2ZERO;
      float nm = fmaxf(mrun, vv);
      srun = srun * fexp2(mrun - nm) + fexp2(vv - nm);
      mrun = nm;
    }
    int t0 = (start > 1) ? start : 1;
    #pragma unroll 2
    for (int t = t0; t < Tt; ++t) {
      float xn = sl[t * 31 + 1 + kk] - lgS[t];
      float xb = blankLp[t];
      float pref = lastP1[t - 1];   // lastPsum == lastP1 bit-exactly
      float Pn2 = lg2add(Pn, pref) + xn;
      float Pb2 = lg2add(Pn, Pb) + xb;
      Pn = Pn2; Pb = Pb2;
      float vv = (t < xlb) ? lg2add(Pn, Pb) : LOG2ZERO;   // off critical path
      float nm = fmaxf(mrun, vv);
      srun = srun * fexp2(mrun - nm) + fexp2(vv - nm);
      mrun = nm;
    }
    curP = (mrun + flog2(srun)) * LN2;       // back to ln domain
  }
  __syncthreads();   // LOGZERO fill + lastP1 complete

  if (tid < 64) {
    if (tid < CB) orow[beam[b * CB + tid]] = curP;
  }
  __syncthreads();
  if (tid == 0) {
    float eosv = (xlb >= 1) ? lastP1[xlb - 1] * LN2 : 0.0f;
    orow[*eosp] = eosv;
    orow[*blankp] = LOGZERO;
  }
}

extern "C" void kernel_launch(void* const* d_in, const int* in_sizes, int n_in,
                              void* d_out, int out_size, void* d_ws, size_t ws_size,
                              hipStream_t stream) {
  (void)n_in; (void)out_size; (void)ws_size;
  const float* x    = (const float*)d_in[0];
  const float* W    = (const float*)d_in[1];
  const float* bias = (const float*)d_in[2];
  const int* xl     = (const int*)d_in[3];
  const int* beam   = (const int*)d_in[5];
  const int* blankp = (const int*)d_in[6];
  const int* eosp   = (const int*)d_in[7];
  const int Ly = in_sizes[4] / Bb;
  const int CB = in_sizes[5] / Bb;

  float* Ssum = (float*)d_ws;                                        // 64 KB
  float* selL = (float*)((char*)d_ws + (size_t)65536);               // 1.94 MB
  unsigned char* Xf8 = (unsigned char*)((char*)d_ws + (size_t)2097152);        // 8 MB
  unsigned char* Wf8 = (unsigned char*)((char*)d_ws + (size_t)(2097152 + 8388608)); // 2 MB
  float* outf = (float*)d_out;

  kPre<<<2568, 256, 0, stream>>>(x, W, Xf8, Wf8, Ssum);
  kA<<<(BT / 128) * (Vv / 256), 256, 0, stream>>>(Xf8, Wf8, bias, beam, blankp, Ssum, selL, CB);
  kC<<<Bb, 256, 0, stream>>>(selL, Ssum, xl, beam, blankp, eosp, outf, Ly, CB);
}